// Round 2
// baseline (340.728 us; speedup 1.0000x reference)
//
#include <hip/hip_runtime.h>
#include <hip/hip_bf16.h>

#define NNODES 50000
#define NEDGES 300000
#define NGRAPH 2048
#define NFEAT  128
#define NHID   256
#define DOUT   32
#define NROWS  50048   // 64-aligned row allocation

typedef __bf16 bf16x8 __attribute__((ext_vector_type(8)));
typedef float  f32x4  __attribute__((ext_vector_type(4)));
typedef unsigned short ushort8v __attribute__((ext_vector_type(8)));
typedef __attribute__((address_space(1))) const void* gas_ptr;
typedef __attribute__((address_space(3))) void* las_ptr;

__device__ __forceinline__ float bf2f(unsigned short u) {
    return __uint_as_float(((unsigned)u) << 16);
}
__device__ __forceinline__ unsigned short f2bf(float f) {
    unsigned u = __float_as_uint(f);
    unsigned r = u + 0x7FFFu + ((u >> 16) & 1u);   // RNE
    return (unsigned short)(r >> 16);
}

// ---------- prep: cast x -> bf16, weights -> bf16 (layer weights pre-swizzled), zero cnt/fill ----
__global__ __launch_bounds__(256) void prep_k(const float* __restrict__ x, unsigned short* __restrict__ x16,
                                              const float* __restrict__ W1, const float* __restrict__ W2,
                                              const float* __restrict__ W3, const float* __restrict__ Wf1,
                                              const float* __restrict__ Wf2,
                                              unsigned short* __restrict__ Wt1, unsigned short* __restrict__ Wt2,
                                              unsigned short* __restrict__ Wt3, unsigned short* __restrict__ Wf1t,
                                              unsigned short* __restrict__ Wf2t,
                                              int* __restrict__ cnt, int* __restrict__ fill) {
    int idx = blockIdx.x * 256 + threadIdx.x;
    if (idx < 800000) {                       // x cast, 8 elems/thread
        int i = idx * 8;
        float4 a = *(const float4*)&x[i];
        float4 b = *(const float4*)&x[i + 4];
        ushort4 lo = { f2bf(a.x), f2bf(a.y), f2bf(a.z), f2bf(a.w) };
        ushort4 hi = { f2bf(b.x), f2bf(b.y), f2bf(b.z), f2bf(b.w) };
        *(ushort4*)&x16[i] = lo;
        *(ushort4*)&x16[i + 4] = hi;
        return;
    }
    int t = idx - 800000;
    if (t < 200704) {
        const float* W; unsigned short* Wt; int K, N, base; bool sw;
        if      (t <  32768) { W = W1;  Wt = Wt1;  K = 128; N = 256; base = 0;      sw = true; }
        else if (t <  98304) { W = W2;  Wt = Wt2;  K = 256; N = 256; base = 32768;  sw = true; }
        else if (t < 163840) { W = W3;  Wt = Wt3;  K = 256; N = 256; base = 98304;  sw = true; }
        else if (t < 196608) { W = Wf1; Wt = Wf1t; K = 256; N = 128; base = 163840; sw = false; }
        else                 { W = Wf2; Wt = Wf2t; K = 128; N = 32;  base = 196608; sw = false; }
        int i = t - base; int n = i / K, k = i - n * K;
        unsigned short v = f2bf(W[(size_t)k * N + n]);
        if (sw) Wt[(k >> 5) * 8192 + n * 32 + (k & 31)] = v;   // sliced layout (N=256)
        else    Wt[i] = v;                                      // row-major [n][K]
        return;
    }
    t -= 200704;
    if (t < NNODES) { cnt[t] = 0; fill[t] = 0; }
}

__global__ __launch_bounds__(256) void edge_hist_k(const int* __restrict__ dst, int* cnt, int E) {
    int e = blockIdx.x * 256 + threadIdx.x;
    if (e < E) atomicAdd(&cnt[dst[e]], 1);
}

// block-level scan + dinv (chunk = 1024 nodes)
__global__ __launch_bounds__(1024) void scan_block_k(const int* __restrict__ cnt, int* __restrict__ rowp,
                                                     int* __restrict__ part, float* __restrict__ dinv, int n) {
    __shared__ int s[1024];
    int tid = threadIdx.x;
    int i = blockIdx.x * 1024 + tid;
    int v = (i < n) ? cnt[i] : 0;
    if (i < n) dinv[i] = rsqrtf((float)(v + 1));   // +1 self-loop
    s[tid] = v;
    __syncthreads();
    for (int off = 1; off < 1024; off <<= 1) {
        int t = (tid >= off) ? s[tid - off] : 0;
        __syncthreads();
        s[tid] += t;
        __syncthreads();
    }
    if (i < n) rowp[i] = s[tid] - v;               // exclusive, pre-offset
    if (tid == 1023) part[blockIdx.x] = s[1023];
}

// scatter + rowp finalize (folds scan_add) + graph-start table (batch sorted)
// adjacency stored interleaved: adj[p] = {src, norm-bits} (single 8B store)
__global__ __launch_bounds__(256) void scatter_k(const int* __restrict__ src, const int* __restrict__ dst,
                                                 const int* __restrict__ rowp_pre, const int* __restrict__ part,
                                                 int* fill, const float* __restrict__ dinv,
                                                 int2* __restrict__ adj,
                                                 int* __restrict__ rowp_fin,
                                                 const int* __restrict__ batch, int* __restrict__ gstart,
                                                 int E, int n, int nb) {
    __shared__ int s[64];
    int tid = threadIdx.x;
    if (tid < 64) s[tid] = (tid < nb) ? part[tid] : 0;
    __syncthreads();
    for (int off = 1; off < 64; off <<= 1) {
        int t = 0;
        if (tid < 64 && tid >= off) t = s[tid - off];
        __syncthreads();
        if (tid < 64) s[tid] += t;
        __syncthreads();
    }
    int gid = blockIdx.x * 256 + tid;
    if (gid <= n) {
        if (gid < n) {
            int ch = gid >> 10;
            int base = (ch == 0) ? 0 : s[ch - 1];
            rowp_fin[gid] = rowp_pre[gid] + base;
        } else {
            rowp_fin[n] = s[nb - 1];
        }
    }
    if (gid < n) {   // graph start offsets: gstart[g] = first node with batch >= g
        int b = batch[gid];
        int prev = (gid == 0) ? -1 : batch[gid - 1];
        for (int g = prev + 1; g <= b; ++g) gstart[g] = gid;
        if (gid == n - 1)
            for (int g = b + 1; g <= NGRAPH; ++g) gstart[g] = n;
    }
    if (gid < E) {
        int ss = src[gid], d = dst[gid];
        int ch = d >> 10;
        int base = (ch == 0) ? 0 : s[ch - 1];
        int p = rowp_pre[d] + base + atomicAdd(&fill[d], 1);
        int2 a; a.x = ss; a.y = __float_as_int(dinv[ss] * dinv[d]);
        adj[p] = a;
    }
}

// ---------- fused aggregate + register-stationary-B MFMA GEMM ----------
// Per 64-row tile: (1) agg phase — K/8-lane streams gather+scale sources directly into an
// XOR-swizzled LDS A-tile (byte ^= (row&7)<<4 fixes the 16-way ds_read_b128 conflict at
// 512B row stride); (2) barrier-free K-loop: A from LDS, B from registers (loaded once,
// persistent block); (3) epilogue via separate LDS tile -> coalesced ushort8 stores.
// 2 syncthreads per tile. Eliminates the Z intermediate round-trip entirely.
template<int K>
__global__ __launch_bounds__(512, 2) void fused_agg_gemm_k(
        const unsigned short* __restrict__ T,    // activations [*][K] bf16
        const int2* __restrict__ adj,            // {src, norm}
        const int* __restrict__ rowp,            // finalized CSR rowptr
        const float* __restrict__ dinv,
        const unsigned short* __restrict__ Bsw,  // pre-swizzled weights [K/32][256][32]
        const float* __restrict__ bias,
        unsigned short* __restrict__ C,          // [*][256] bf16
        int M, int flags, int ntiles) {
    constexpr int CH = K / 8;                    // 16B chunks per row (16 or 32)
    constexpr int NS = 512 / CH;                 // streams per block (32 or 16)
    constexpr int RPS = 64 / NS;                 // rows per stream (2 or 4)
    __shared__ unsigned short At[64 * K];        // swizzled A tile (16/32 KB)
    __shared__ unsigned short Et[64 * 264];      // epilogue tile (33.8 KB)
    const int tid = threadIdx.x;
    const int lane = tid & 63;
    const int wave = tid >> 6;                   // 0..7
    const int m = lane & 15, q = lane >> 4;
    const int wr = (wave >> 2) * 32;             // 0 / 32
    const int wc = (wave & 3) * 64;              // 0 / 64 / 128 / 192
    const int st = tid / CH;                     // stream id
    const int li = tid % CH;                     // chunk within row

    // load this wave's B slice (64 cols x K) into registers once
    bf16x8 breg[K / 32][4];
#pragma unroll
    for (int kt = 0; kt < K / 32; ++kt)
#pragma unroll
        for (int j = 0; j < 4; ++j)
            breg[kt][j] = *(const bf16x8*)&Bsw[kt * 8192 + (wc + j * 16 + m) * 32 + q * 8];

    char* Atb = (char*)At;
    const ushort8v* tp = (const ushort8v*)T;

    for (int t = blockIdx.x; t < ntiles; t += gridDim.x) {
        const int rowBase = t * 64;
        // ---- agg phase: gather into swizzled LDS A-tile ----
#pragma unroll
        for (int s = 0; s < RPS; ++s) {
            int lr = st * RPS + s;
            int nd = rowBase + lr;
            float ac[8] = {0.f, 0.f, 0.f, 0.f, 0.f, 0.f, 0.f, 0.f};
            if (nd < NNODES) {
                float di = dinv[nd], sw = di * di;
                ushort8v u = tp[(size_t)nd * CH + li];
#pragma unroll
                for (int k = 0; k < 8; ++k) ac[k] = bf2f(u[k]) * sw;
                int e0 = rowp[nd], e1 = rowp[nd + 1];
                for (int e = e0; e < e1; e += 8) {
                    int c[8]; float w[8];
#pragma unroll
                    for (int j = 0; j < 8; ++j) {
                        int ee = e + j;
                        bool v = ee < e1;
                        int2 a = v ? adj[ee] : make_int2(0, 0);
                        c[j] = a.x; w[j] = __int_as_float(a.y);
                    }
                    ushort8v mm[8];
#pragma unroll
                    for (int j = 0; j < 8; ++j) mm[j] = tp[(size_t)c[j] * CH + li];
#pragma unroll
                    for (int j = 0; j < 8; ++j)
#pragma unroll
                        for (int k = 0; k < 8; ++k)
                            ac[k] += bf2f(mm[j][k]) * w[j];
                }
            }
            ushort8v o;
#pragma unroll
            for (int k = 0; k < 8; ++k) o[k] = f2bf(ac[k]);
            int byteo = (lr * (K * 2) + li * 16) ^ ((lr & 7) << 4);
            *(ushort8v*)(Atb + byteo) = o;
        }
        __syncthreads();   // A-tile ready (also: prev tile's Et stores done)

        // ---- GEMM K-loop: LDS A (swizzled) x register B ----
        f32x4 acc[2][4] = {};
#pragma unroll
        for (int kt = 0; kt < K / 32; ++kt) {
            bf16x8 af[2];
#pragma unroll
            for (int i = 0; i < 2; ++i) {
                int lr = wr + i * 16 + m;
                int byteo = (lr * (K * 2) + kt * 64 + q * 16) ^ ((lr & 7) << 4);
                af[i] = *(const bf16x8*)(Atb + byteo);
            }
#pragma unroll
            for (int i = 0; i < 2; ++i)
#pragma unroll
                for (int j = 0; j < 4; ++j)
                    acc[i][j] = __builtin_amdgcn_mfma_f32_16x16x32_bf16(af[i], breg[kt][j], acc[i][j], 0, 0, 0);
        }

        // ---- epilogue: repack to Et, coalesced stores ----
#pragma unroll
        for (int i = 0; i < 2; ++i) {
#pragma unroll
            for (int j = 0; j < 4; ++j) {
                int c = wc + j * 16 + m;
                float bv = (flags & 2) ? bias[c] : 0.f;
#pragma unroll
                for (int r = 0; r < 4; ++r) {
                    float v = acc[i][j][r] + bv;
                    if (flags & 1) v = fmaxf(v, 0.f);
                    Et[(wr + i * 16 + q * 4 + r) * 264 + c] = f2bf(v);
                }
            }
        }
        __syncthreads();   // Et ready, all K-loop reads of At done
#pragma unroll
        for (int u0 = 0; u0 < 4; ++u0) {
            int u = u0 * 512 + tid;
            int row = u >> 5, cc = (u & 31) * 8;
            int rr = rowBase + row;
            if (rr < M)
                *(ushort8v*)&C[(size_t)rr * 256 + cc] = *(const ushort8v*)&Et[row * 264 + cc];
        }
        // next iteration's agg writes At only after its syncthreads-A, which
        // all waves reach after completing these stores -> no extra barrier
    }
}

// ---------- pooling: one block per graph, bounds from precomputed gstart ----------
__global__ __launch_bounds__(256) void pool_k(const unsigned short* __restrict__ h,
                                              const int* __restrict__ gstart,
                                              unsigned short* __restrict__ hg) {
    __shared__ float red[4][256];
    int g = blockIdx.x;
    int wave = threadIdx.x >> 6, lane = threadIdx.x & 63;
    int s = gstart[g], e = gstart[g + 1];
    const ushort4* hp = (const ushort4*)h;
    float4 acc = make_float4(0.f, 0.f, 0.f, 0.f);
    for (int i = s + wave; i < e; i += 4) {
        ushort4 v = hp[(size_t)i * 64 + lane];
        acc.x += bf2f(v.x); acc.y += bf2f(v.y); acc.z += bf2f(v.z); acc.w += bf2f(v.w);
    }
    *(float4*)&red[wave][lane * 4] = acc;
    __syncthreads();
    if (wave == 0) {
        float inv = 1.f / fmaxf((float)(e - s), 1.f);
        float v0 = red[0][lane*4+0] + red[1][lane*4+0] + red[2][lane*4+0] + red[3][lane*4+0];
        float v1 = red[0][lane*4+1] + red[1][lane*4+1] + red[2][lane*4+1] + red[3][lane*4+1];
        float v2 = red[0][lane*4+2] + red[1][lane*4+2] + red[2][lane*4+2] + red[3][lane*4+2];
        float v3 = red[0][lane*4+3] + red[1][lane*4+3] + red[2][lane*4+3] + red[3][lane*4+3];
        ushort4 o = { f2bf(v0 * inv), f2bf(v1 * inv), f2bf(v2 * inv), f2bf(v3 * inv) };
        ((ushort4*)(hg + (size_t)g * NHID))[lane] = o;
    }
}

// ---------- MLP head, fused: out = relu(HG@Wf1t^T + bf1) @ Wf2t^T + bf2 ----------
__global__ __launch_bounds__(256) void mlp_head_k(const unsigned short* __restrict__ HG,
                                                  const unsigned short* __restrict__ Wf1t,  // [128][256]
                                                  const unsigned short* __restrict__ Wf2t,  // [32][128]
                                                  const float* __restrict__ bf1, const float* __restrict__ bf2,
                                                  float* __restrict__ out) {
    __shared__ unsigned short As1[128 * 32];   // 8 KB
    __shared__ unsigned short Bs1[128 * 32];   // 8 KB
    __shared__ unsigned short R[128 * 128];    // 32 KB
    __shared__ unsigned short Bs2[32 * 128];   // 8 KB
    const int tid = threadIdx.x;
    const int lane = tid & 63, wave = tid >> 6;
    const int m = lane & 15, q = lane >> 4;
    const int rowBase = blockIdx.x * 128;
    const int wr = (wave >> 1) * 64;
    const int wc = (wave & 1) * 64;

#pragma unroll
    for (int c2 = 0; c2 < 2; ++c2) {
        const unsigned short* g = &Wf2t[(c2 * 256 + tid) * 8];
        __builtin_amdgcn_global_load_lds((gas_ptr)g, (las_ptr)&Bs2[(c2 * 256 + wave * 64) * 8], 16, 0, 0);
    }

    f32x4 acc[4][4] = {};
    for (int kt = 0; kt < 256; kt += 32) {
#pragma unroll
        for (int c2 = 0; c2 < 2; ++c2) {
            int u = c2 * 256 + tid;
            int row = u >> 2, kp = u & 3;
            const unsigned short* ga = &HG[(size_t)(rowBase + row) * 256 + kt + kp * 8];
            const unsigned short* gb = &Wf1t[(size_t)row * 256 + kt + kp * 8];
            __builtin_amdgcn_global_load_lds((gas_ptr)ga, (las_ptr)&As1[(c2 * 256 + wave * 64) * 8], 16, 0, 0);
            __builtin_amdgcn_global_load_lds((gas_ptr)gb, (las_ptr)&Bs1[(c2 * 256 + wave * 64) * 8], 16, 0, 0);
        }
        __syncthreads();
        bf16x8 af[4], bfr[4];
#pragma unroll
        for (int i = 0; i < 4; ++i) af[i] = *(const bf16x8*)&As1[(wr + i * 16 + m) * 32 + q * 8];
#pragma unroll
        for (int j = 0; j < 4; ++j) bfr[j] = *(const bf16x8*)&Bs1[(wc + j * 16 + m) * 32 + q * 8];
#pragma unroll
        for (int i = 0; i < 4; ++i)
#pragma unroll
            for (int j = 0; j < 4; ++j)
                acc[i][j] = __builtin_amdgcn_mfma_f32_16x16x32_bf16(af[i], bfr[j], acc[i][j], 0, 0, 0);
        __syncthreads();
    }
#pragma unroll
    for (int i = 0; i < 4; ++i)
#pragma unroll
        for (int j = 0; j < 4; ++j) {
            int c = wc + j * 16 + m;
            float bv = bf1[c];
#pragma unroll
            for (int r = 0; r < 4; ++r) {
                int rr = wr + i * 16 + q * 4 + r;
                R[rr * 128 + c] = f2bf(fmaxf(acc[i][j][r] + bv, 0.f));
            }
        }
    __syncthreads();

    const int wr2 = wave * 32;
    f32x4 acc2[2][2] = {};
#pragma unroll
    for (int s2 = 0; s2 < 4; ++s2) {
        bf16x8 af2[2], bf22[2];
#pragma unroll
        for (int i = 0; i < 2; ++i) af2[i] = *(const bf16x8*)&R[(wr2 + i * 16 + m) * 128 + s2 * 32 + q * 8];
#pragma unroll
        for (int ct = 0; ct < 2; ++ct) bf22[ct] = *(const bf16x8*)&Bs2[(ct * 16 + m) * 128 + s2 * 32 + q * 8];
#pragma unroll
        for (int i = 0; i < 2; ++i)
#pragma unroll
            for (int ct = 0; ct < 2; ++ct)
                acc2[i][ct] = __builtin_amdgcn_mfma_f32_16x16x32_bf16(af2[i], bf22[ct], acc2[i][ct], 0, 0, 0);
    }
#pragma unroll
    for (int i = 0; i < 2; ++i)
#pragma unroll
        for (int ct = 0; ct < 2; ++ct) {
            int c = ct * 16 + m;
            float bv = bf2[c];
#pragma unroll
            for (int r = 0; r < 4; ++r) {
                int rr = rowBase + wr2 + i * 16 + q * 4 + r;
                out[(size_t)rr * 32 + c] = acc2[i][ct][r] + bv;
            }
        }
}

extern "C" void kernel_launch(void* const* d_in, const int* in_sizes, int n_in,
                              void* d_out, int out_size, void* d_ws, size_t ws_size,
                              hipStream_t stream) {
    const float* x    = (const float*)d_in[0];
    const int*   ei   = (const int*)d_in[1];
    const int*   batch= (const int*)d_in[2];
    const float* W1   = (const float*)d_in[3];
    const float* b1   = (const float*)d_in[4];
    const float* W2   = (const float*)d_in[5];
    const float* b2   = (const float*)d_in[6];
    const float* W3   = (const float*)d_in[7];
    const float* b3   = (const float*)d_in[8];
    const float* Wf1  = (const float*)d_in[9];
    const float* bf1  = (const float*)d_in[10];
    const float* Wf2  = (const float*)d_in[11];
    const float* bf2  = (const float*)d_in[12];
    float* out = (float*)d_out;

    const int* e_src = ei;
    const int* e_dst = ei + NEDGES;

    char* ws = (char*)d_ws;
    size_t off = 0;
    auto alloc = [&](size_t bytes) -> void* {
        void* p = (void*)(ws + off);
        off += (bytes + 255) & ~(size_t)255;
        return p;
    };
    unsigned short* X16 = (unsigned short*)alloc((size_t)NROWS * NFEAT * 2);
    unsigned short* Ha  = (unsigned short*)alloc((size_t)NROWS * NHID * 2);    // layer activations A
    unsigned short* Hb  = (unsigned short*)alloc((size_t)NROWS * NHID * 2);    // layer activations B
    unsigned short* Wt1 = (unsigned short*)alloc((size_t)NHID * NFEAT * 2);    // swizzled [4][256][32]
    unsigned short* Wt2 = (unsigned short*)alloc((size_t)NHID * NHID * 2);     // swizzled [8][256][32]
    unsigned short* Wt3 = (unsigned short*)alloc((size_t)NHID * NHID * 2);     // swizzled [8][256][32]
    unsigned short* Wf1t= (unsigned short*)alloc((size_t)NFEAT * NHID * 2);
    unsigned short* Wf2t= (unsigned short*)alloc((size_t)DOUT * NFEAT * 2);
    unsigned short* HG  = (unsigned short*)alloc((size_t)NGRAPH * NHID * 2);
    float* dinv = (float*)alloc((size_t)NNODES * 4);
    int*   cnt  = (int*)alloc((size_t)NNODES * 4);
    int*   fill = (int*)alloc((size_t)NNODES * 4);
    int*   rowp = (int*)alloc((size_t)(NNODES + 1) * 4);   // pre-offset
    int*   rowf = (int*)alloc((size_t)(NNODES + 1) * 4);   // finalized
    int2*  adj  = (int2*)alloc((size_t)NEDGES * 8);        // interleaved {col, nrm}
    int*   part = (int*)alloc((size_t)64 * 4);
    int*   gstart = (int*)alloc((size_t)(NGRAPH + 1) * 4);
    (void)alloc(131072);   // tail pad

    const int nb = (NNODES + 1023) / 1024;   // 49

    // ---- prep: casts + zero cnt/fill ----
    hipLaunchKernelGGL(prep_k, dim3((1050704 + 255) / 256), dim3(256), 0, stream,
                       x, X16, W1, W2, W3, Wf1, Wf2, Wt1, Wt2, Wt3, Wf1t, Wf2t, cnt, fill);
    // ---- CSR + norm + graph starts ----
    hipLaunchKernelGGL(edge_hist_k, dim3((NEDGES + 255) / 256), dim3(256), 0, stream, e_dst, cnt, NEDGES);
    hipLaunchKernelGGL(scan_block_k, dim3(nb), dim3(1024), 0, stream, cnt, rowp, part, dinv, NNODES);
    hipLaunchKernelGGL(scatter_k, dim3((NEDGES + 255) / 256), dim3(256), 0, stream,
                       e_src, e_dst, rowp, part, fill, dinv, adj, rowf, batch, gstart,
                       NEDGES, NNODES, nb);

    const int ntiles = NROWS / 64;          // 782
    // ---- layer 1: Ha = relu((A_hat X) @ W1 + b1), fused ----
    hipLaunchKernelGGL((fused_agg_gemm_k<128>), dim3(512), dim3(512), 0, stream,
                       X16, adj, rowf, dinv, Wt1, b1, Ha, NNODES, 3, ntiles);
    // ---- layer 2: Hb = relu((A_hat Ha) @ W2 + b2), fused ----
    hipLaunchKernelGGL((fused_agg_gemm_k<256>), dim3(512), dim3(512), 0, stream,
                       Ha, adj, rowf, dinv, Wt2, b2, Hb, NNODES, 3, ntiles);
    // ---- layer 3: Ha = relu((A_hat Hb) @ W3 + b3), fused ----
    hipLaunchKernelGGL((fused_agg_gemm_k<256>), dim3(512), dim3(512), 0, stream,
                       Hb, adj, rowf, dinv, Wt3, b3, Ha, NNODES, 3, ntiles);

    // ---- pool (one block/graph, no binary search) ----
    hipLaunchKernelGGL(pool_k, dim3(NGRAPH), dim3(256), 0, stream, Ha, gstart, HG);

    // ---- MLP head (fused) ----
    hipLaunchKernelGGL(mlp_head_k, dim3(NGRAPH / 128), dim3(256), 0, stream,
                       HG, Wf1t, Wf2t, bf1, bf2, out);
}

// Round 3
// 280.161 us; speedup vs baseline: 1.2162x; 1.2162x over previous
//
#include <hip/hip_runtime.h>
#include <hip/hip_bf16.h>

#define NNODES 50000
#define NEDGES 300000
#define NGRAPH 2048
#define NFEAT  128
#define NHID   256
#define DOUT   32
#define NROWS  50048   // 64-aligned row allocation

typedef __bf16 bf16x8 __attribute__((ext_vector_type(8)));
typedef float  f32x4  __attribute__((ext_vector_type(4)));
typedef unsigned short ushort8v __attribute__((ext_vector_type(8)));
typedef __attribute__((address_space(1))) const void* gas_ptr;
typedef __attribute__((address_space(3))) void* las_ptr;

__device__ __forceinline__ float bf2f(unsigned short u) {
    return __uint_as_float(((unsigned)u) << 16);
}
__device__ __forceinline__ unsigned short f2bf(float f) {
    unsigned u = __float_as_uint(f);
    unsigned r = u + 0x7FFFu + ((u >> 16) & 1u);   // RNE
    return (unsigned short)(r >> 16);
}

// Activation arrays (X16, Za, Ha, Zb) are stored XOR-swizzled: 16B chunk ch of row r
// lives at chunk index (ch ^ (r&7)). Writers (prep, agg, gemm-epilogue) and per-lane
// readers (agg, pool) apply the XOR; gemm staging copies bytes linearly into LDS so
// the swizzle carries over and ds_read_b128 at 512B row stride is bank-conflict-free.

// ---------- prep: cast x -> bf16 (swizzled), weights -> bf16, zero cnt/fill/adj8 ----
__global__ __launch_bounds__(256) void prep_k(const float* __restrict__ x, unsigned short* __restrict__ x16,
                                              const float* __restrict__ W1, const float* __restrict__ W2,
                                              const float* __restrict__ W3, const float* __restrict__ Wf1,
                                              const float* __restrict__ Wf2,
                                              unsigned short* __restrict__ Wt1, unsigned short* __restrict__ Wt2,
                                              unsigned short* __restrict__ Wt3, unsigned short* __restrict__ Wf1t,
                                              unsigned short* __restrict__ Wf2t,
                                              int* __restrict__ cnt, int* __restrict__ fill,
                                              int4* __restrict__ adj8z) {
    int idx = blockIdx.x * 256 + threadIdx.x;
    if (idx < 800000) {                       // x cast, one 16B chunk/thread, swizzled store
        int i = idx * 8;
        float4 a = *(const float4*)&x[i];
        float4 b = *(const float4*)&x[i + 4];
        ushort8v o = { f2bf(a.x), f2bf(a.y), f2bf(a.z), f2bf(a.w),
                       f2bf(b.x), f2bf(b.y), f2bf(b.z), f2bf(b.w) };
        int row = idx >> 4, ch = idx & 15;
        ((ushort8v*)x16)[(size_t)(row << 4) | (ch ^ (row & 7))] = o;
        return;
    }
    int t = idx - 800000;
    if (t < 200704) {
        const float* W; unsigned short* Wt; int K, N, base; bool sw;
        if      (t <  32768) { W = W1;  Wt = Wt1;  K = 128; N = 256; base = 0;      sw = true; }
        else if (t <  98304) { W = W2;  Wt = Wt2;  K = 256; N = 256; base = 32768;  sw = true; }
        else if (t < 163840) { W = W3;  Wt = Wt3;  K = 256; N = 256; base = 98304;  sw = true; }
        else if (t < 196608) { W = Wf1; Wt = Wf1t; K = 256; N = 128; base = 163840; sw = false; }
        else                 { W = Wf2; Wt = Wf2t; K = 128; N = 32;  base = 196608; sw = false; }
        int i = t - base; int n = i / K, k = i - n * K;
        unsigned short v = f2bf(W[(size_t)k * N + n]);
        if (sw) Wt[(k >> 5) * 8192 + n * 32 + (k & 31)] = v;   // sliced layout (N=256)
        else    Wt[i] = v;                                      // row-major [n][K]
        return;
    }
    t -= 200704;
    if (t < NNODES) { cnt[t] = 0; fill[t] = 0; return; }
    t -= NNODES;
    if (t < 200000) { int4 z4 = {0, 0, 0, 0}; adj8z[t] = z4; }   // zero inline slots
}

__global__ __launch_bounds__(256) void edge_hist_k(const int* __restrict__ dst, int* cnt, int E) {
    int e = blockIdx.x * 256 + threadIdx.x;
    if (e < E) atomicAdd(&cnt[dst[e]], 1);
}

// block-level scan + dinv + node header {deg, dinv^2} (chunk = 1024 nodes)
__global__ __launch_bounds__(1024) void scan_block_k(const int* __restrict__ cnt, int* __restrict__ rowp,
                                                     int* __restrict__ part, float* __restrict__ dinv,
                                                     int2* __restrict__ hdr, int n) {
    __shared__ int s[1024];
    int tid = threadIdx.x;
    int i = blockIdx.x * 1024 + tid;
    int v = (i < n) ? cnt[i] : 0;
    if (i < n) {
        float dv = rsqrtf((float)(v + 1));   // +1 self-loop
        dinv[i] = dv;
        hdr[i] = make_int2(v, __float_as_int(dv * dv));
    }
    s[tid] = v;
    __syncthreads();
    for (int off = 1; off < 1024; off <<= 1) {
        int t = (tid >= off) ? s[tid - off] : 0;
        __syncthreads();
        s[tid] += t;
        __syncthreads();
    }
    if (i < n) rowp[i] = s[tid] - v;               // exclusive, pre-offset
    if (tid == 1023) part[blockIdx.x] = s[1023];
}

// scatter: first 8 edges/dst -> inline slots adj8; rest -> CSR adj (entries >=8 only).
// Also finalizes rowp and builds graph-start table.
__global__ __launch_bounds__(256) void scatter_k(const int* __restrict__ src, const int* __restrict__ dst,
                                                 const int* __restrict__ rowp_pre, const int* __restrict__ part,
                                                 int* fill, const float* __restrict__ dinv,
                                                 int2* __restrict__ adj8, int2* __restrict__ adj,
                                                 int* __restrict__ rowp_fin,
                                                 const int* __restrict__ batch, int* __restrict__ gstart,
                                                 int E, int n, int nb) {
    __shared__ int s[64];
    int tid = threadIdx.x;
    if (tid < 64) s[tid] = (tid < nb) ? part[tid] : 0;
    __syncthreads();
    for (int off = 1; off < 64; off <<= 1) {
        int t = 0;
        if (tid < 64 && tid >= off) t = s[tid - off];
        __syncthreads();
        if (tid < 64) s[tid] += t;
        __syncthreads();
    }
    int gid = blockIdx.x * 256 + tid;
    if (gid <= n) {
        if (gid < n) {
            int ch = gid >> 10;
            int base = (ch == 0) ? 0 : s[ch - 1];
            rowp_fin[gid] = rowp_pre[gid] + base;
        } else {
            rowp_fin[n] = s[nb - 1];
        }
    }
    if (gid < n) {   // graph start offsets: gstart[g] = first node with batch >= g
        int b = batch[gid];
        int prev = (gid == 0) ? -1 : batch[gid - 1];
        for (int g = prev + 1; g <= b; ++g) gstart[g] = gid;
        if (gid == n - 1)
            for (int g = b + 1; g <= NGRAPH; ++g) gstart[g] = n;
    }
    if (gid < E) {
        int ss = src[gid], d = dst[gid];
        int f = atomicAdd(&fill[d], 1);
        int2 a; a.x = ss; a.y = __float_as_int(dinv[ss] * dinv[d]);
        if (f < 8) {
            adj8[d * 8 + f] = a;
        } else {
            int ch = d >> 10;
            int base = (ch == 0) ? 0 : s[ch - 1];
            adj[rowp_pre[d] + base + f] = a;
        }
    }
}

// ---------- slot-based aggregation: z = A_hat @ T, one node per CH-lane group ----------
// All addresses derive from the node id (hdr, slots, self-row issue immediately);
// gathers depend only on the slot load -> single dependent-latency hop. No shuffles,
// fully coalesced swizzled stores. deg>8 overflow via masked x4 CSR loop (rare).
template<int CH>   // 16B chunks per row: 16 (128-wide) or 32 (256-wide)
__global__ __launch_bounds__(256) void agg_k(const unsigned short* __restrict__ T,
                                             const int4* __restrict__ adj8,
                                             const int2* __restrict__ hdr,
                                             const int* __restrict__ rowf,
                                             const int2* __restrict__ adj,
                                             unsigned short* __restrict__ z, int n) {
    int g  = threadIdx.x / CH;
    int li = threadIdx.x % CH;
    int node = blockIdx.x * (256 / CH) + g;
    if (node >= n) return;
    const ushort8v* tp = (const ushort8v*)T;
    int2 h = hdr[node];
    int deg = h.x;
    float sw = __int_as_float(h.y);
    ushort8v u = tp[(size_t)node * CH + (li ^ (node & 7))];
    int4 s4[4];
#pragma unroll
    for (int j = 0; j < 4; ++j) s4[j] = adj8[node * 4 + j];
    float ac[8];
#pragma unroll
    for (int k = 0; k < 8; ++k) ac[k] = bf2f(u[k]) * sw;
    int c[8]; float w[8];
#pragma unroll
    for (int j = 0; j < 4; ++j) {
        c[2 * j]     = s4[j].x; w[2 * j]     = __int_as_float(s4[j].y);
        c[2 * j + 1] = s4[j].z; w[2 * j + 1] = __int_as_float(s4[j].w);
    }
    ushort8v mm[8];
#pragma unroll
    for (int j = 0; j < 8; ++j) mm[j] = tp[(size_t)c[j] * CH + (li ^ (c[j] & 7))];
#pragma unroll
    for (int j = 0; j < 8; ++j)
#pragma unroll
        for (int k = 0; k < 8; ++k)
            ac[k] += bf2f(mm[j][k]) * w[j];
    if (deg > 8) {   // overflow: CSR entries >= 8
        int e0 = rowf[node], e1 = e0 + deg;
        for (int e = e0 + 8; e < e1; e += 4) {
            int2 a2[4];
#pragma unroll
            for (int j = 0; j < 4; ++j) {
                int ee = e + j;
                a2[j] = (ee < e1) ? adj[ee] : make_int2(0, 0);
            }
            ushort8v m2[4];
#pragma unroll
            for (int j = 0; j < 4; ++j) m2[j] = tp[(size_t)a2[j].x * CH + (li ^ (a2[j].x & 7))];
#pragma unroll
            for (int j = 0; j < 4; ++j)
#pragma unroll
                for (int k = 0; k < 8; ++k)
                    ac[k] += bf2f(m2[j][k]) * __int_as_float(a2[j].y);
        }
    }
    ushort8v o;
#pragma unroll
    for (int k = 0; k < 8; ++k) o[k] = f2bf(ac[k]);
    ((ushort8v*)z)[(size_t)node * CH + (li ^ (node & 7))] = o;
}

// ---------- MFMA GEMM: DMA-staged swizzled A-tile + register-stationary B ----------
// Per 64-row tile: global_load_lds the (pre-swizzled) A-tile (32KB in flight/block),
// barrier, swizzled ds_read_b128 + MFMA against register B, epilogue via LDS repack
// -> coalesced swizzled stores. 2 barriers/tile; 2 blocks/CU overlap staging/compute.
template<int K>
__global__ __launch_bounds__(512, 2) void gemm_k(const unsigned short* __restrict__ A,
                                                 const unsigned short* __restrict__ Bsw,
                                                 const float* __restrict__ bias,
                                                 unsigned short* __restrict__ C,
                                                 int M, int flags, int ntiles) {
    constexpr int CPR = K / 8;                 // 16B chunks per row
    constexpr int LP  = (64 * CPR) / 512;     // staging issues per thread (2 or 4)
    __shared__ unsigned short At[64 * K];      // swizzled A tile (16/32 KB)
    __shared__ unsigned short Et[64 * 264];    // epilogue tile (33.8 KB)
    const int tid = threadIdx.x;
    const int lane = tid & 63;
    const int wave = tid >> 6;                 // 0..7
    const int m = lane & 15, q = lane >> 4;
    const int wr = (wave >> 2) * 32;           // 0 / 32
    const int wc = (wave & 3) * 64;            // 0 / 64 / 128 / 192

    // load this wave's B slice (64 cols x K) into registers once
    bf16x8 breg[K / 32][4];
#pragma unroll
    for (int kt = 0; kt < K / 32; ++kt)
#pragma unroll
        for (int j = 0; j < 4; ++j)
            breg[kt][j] = *(const bf16x8*)&Bsw[kt * 8192 + (wc + j * 16 + m) * 32 + q * 8];

    for (int t = blockIdx.x; t < ntiles; t += gridDim.x) {
        const size_t cbase = (size_t)t * 64 * CPR;   // tile base (16B-chunk units)
        // stage A-tile: linear byte copy of the pre-swizzled global rows
#pragma unroll
        for (int p = 0; p < LP; ++p) {
            int u = p * 512 + tid;
            __builtin_amdgcn_global_load_lds((gas_ptr)(A + (cbase + u) * 8),
                                             (las_ptr)&At[(p * 512 + wave * 64) * 8], 16, 0, 0);
        }
        __syncthreads();   // staging complete (also orders vs prev tile's At reads)

        f32x4 acc[2][4] = {};
#pragma unroll
        for (int kt = 0; kt < K / 32; ++kt) {
            bf16x8 af[2];
#pragma unroll
            for (int i = 0; i < 2; ++i) {
                int lr = wr + i * 16 + m;
                af[i] = *(const bf16x8*)&At[(lr * CPR + ((kt * 4 + q) ^ (lr & 7))) * 8];
            }
#pragma unroll
            for (int i = 0; i < 2; ++i)
#pragma unroll
                for (int j = 0; j < 4; ++j)
                    acc[i][j] = __builtin_amdgcn_mfma_f32_16x16x32_bf16(af[i], breg[kt][j], acc[i][j], 0, 0, 0);
        }

        // epilogue: repack to Et, then coalesced swizzled stores
#pragma unroll
        for (int i = 0; i < 2; ++i) {
#pragma unroll
            for (int j = 0; j < 4; ++j) {
                int c = wc + j * 16 + m;
                float bv = (flags & 2) ? bias[c] : 0.f;
#pragma unroll
                for (int r = 0; r < 4; ++r) {
                    float v = acc[i][j][r] + bv;
                    if (flags & 1) v = fmaxf(v, 0.f);
                    Et[(wr + i * 16 + q * 4 + r) * 264 + c] = f2bf(v);
                }
            }
        }
        __syncthreads();   // Et ready; all At reads this tile complete
#pragma unroll
        for (int u0 = 0; u0 < 4; ++u0) {
            int u = u0 * 512 + tid;
            int row = u >> 5, cc = u & 31;
            int rr = t * 64 + row;
            if (rr < M)
                ((ushort8v*)C)[(size_t)rr * 32 + (cc ^ (rr & 7))] = *(const ushort8v*)&Et[row * 264 + cc * 8];
        }
    }
}

// ---------- pooling: one block per graph, swizzled reads, gstart bounds ----------
__global__ __launch_bounds__(256) void pool_k(const unsigned short* __restrict__ h,
                                              const int* __restrict__ gstart,
                                              unsigned short* __restrict__ hg) {
    __shared__ float red[4][256];
    int g = blockIdx.x;
    int wave = threadIdx.x >> 6, lane = threadIdx.x & 63;
    int s = gstart[g], e = gstart[g + 1];
    int ch = lane >> 1, sub = lane & 1;
    const ushort4* hp = (const ushort4*)h;
    float4 acc = make_float4(0.f, 0.f, 0.f, 0.f);
    for (int i = s + wave; i < e; i += 4) {
        ushort4 v = hp[((size_t)i * 32 + (ch ^ (i & 7))) * 2 + sub];
        acc.x += bf2f(v.x); acc.y += bf2f(v.y); acc.z += bf2f(v.z); acc.w += bf2f(v.w);
    }
    *(float4*)&red[wave][lane * 4] = acc;
    __syncthreads();
    if (wave == 0) {
        float inv = 1.f / fmaxf((float)(e - s), 1.f);
        float v0 = red[0][lane*4+0] + red[1][lane*4+0] + red[2][lane*4+0] + red[3][lane*4+0];
        float v1 = red[0][lane*4+1] + red[1][lane*4+1] + red[2][lane*4+1] + red[3][lane*4+1];
        float v2 = red[0][lane*4+2] + red[1][lane*4+2] + red[2][lane*4+2] + red[3][lane*4+2];
        float v3 = red[0][lane*4+3] + red[1][lane*4+3] + red[2][lane*4+3] + red[3][lane*4+3];
        ushort4 o = { f2bf(v0 * inv), f2bf(v1 * inv), f2bf(v2 * inv), f2bf(v3 * inv) };
        ((ushort4*)(hg + (size_t)g * NHID))[lane] = o;
    }
}

// ---------- MLP head, fused: out = relu(HG@Wf1t^T + bf1) @ Wf2t^T + bf2 ----------
__global__ __launch_bounds__(256) void mlp_head_k(const unsigned short* __restrict__ HG,
                                                  const unsigned short* __restrict__ Wf1t,  // [128][256]
                                                  const unsigned short* __restrict__ Wf2t,  // [32][128]
                                                  const float* __restrict__ bf1, const float* __restrict__ bf2,
                                                  float* __restrict__ out) {
    __shared__ unsigned short As1[128 * 32];   // 8 KB
    __shared__ unsigned short Bs1[128 * 32];   // 8 KB
    __shared__ unsigned short R[128 * 128];    // 32 KB
    __shared__ unsigned short Bs2[32 * 128];   // 8 KB
    const int tid = threadIdx.x;
    const int lane = tid & 63, wave = tid >> 6;
    const int m = lane & 15, q = lane >> 4;
    const int rowBase = blockIdx.x * 128;
    const int wr = (wave >> 1) * 64;
    const int wc = (wave & 1) * 64;

#pragma unroll
    for (int c2 = 0; c2 < 2; ++c2) {
        const unsigned short* g = &Wf2t[(c2 * 256 + tid) * 8];
        __builtin_amdgcn_global_load_lds((gas_ptr)g, (las_ptr)&Bs2[(c2 * 256 + wave * 64) * 8], 16, 0, 0);
    }

    f32x4 acc[4][4] = {};
    for (int kt = 0; kt < 256; kt += 32) {
#pragma unroll
        for (int c2 = 0; c2 < 2; ++c2) {
            int u = c2 * 256 + tid;
            int row = u >> 2, kp = u & 3;
            const unsigned short* ga = &HG[(size_t)(rowBase + row) * 256 + kt + kp * 8];
            const unsigned short* gb = &Wf1t[(size_t)row * 256 + kt + kp * 8];
            __builtin_amdgcn_global_load_lds((gas_ptr)ga, (las_ptr)&As1[(c2 * 256 + wave * 64) * 8], 16, 0, 0);
            __builtin_amdgcn_global_load_lds((gas_ptr)gb, (las_ptr)&Bs1[(c2 * 256 + wave * 64) * 8], 16, 0, 0);
        }
        __syncthreads();
        bf16x8 af[4], bfr[4];
#pragma unroll
        for (int i = 0; i < 4; ++i) af[i] = *(const bf16x8*)&As1[(wr + i * 16 + m) * 32 + q * 8];
#pragma unroll
        for (int j = 0; j < 4; ++j) bfr[j] = *(const bf16x8*)&Bs1[(wc + j * 16 + m) * 32 + q * 8];
#pragma unroll
        for (int i = 0; i < 4; ++i)
#pragma unroll
            for (int j = 0; j < 4; ++j)
                acc[i][j] = __builtin_amdgcn_mfma_f32_16x16x32_bf16(af[i], bfr[j], acc[i][j], 0, 0, 0);
        __syncthreads();
    }
#pragma unroll
    for (int i = 0; i < 4; ++i)
#pragma unroll
        for (int j = 0; j < 4; ++j) {
            int c = wc + j * 16 + m;
            float bv = bf1[c];
#pragma unroll
            for (int r = 0; r < 4; ++r) {
                int rr = wr + i * 16 + q * 4 + r;
                R[rr * 128 + c] = f2bf(fmaxf(acc[i][j][r] + bv, 0.f));
            }
        }
    __syncthreads();

    const int wr2 = wave * 32;
    f32x4 acc2[2][2] = {};
#pragma unroll
    for (int s2 = 0; s2 < 4; ++s2) {
        bf16x8 af2[2], bf22[2];
#pragma unroll
        for (int i = 0; i < 2; ++i) af2[i] = *(const bf16x8*)&R[(wr2 + i * 16 + m) * 128 + s2 * 32 + q * 8];
#pragma unroll
        for (int ct = 0; ct < 2; ++ct) bf22[ct] = *(const bf16x8*)&Bs2[(ct * 16 + m) * 128 + s2 * 32 + q * 8];
#pragma unroll
        for (int i = 0; i < 2; ++i)
#pragma unroll
            for (int ct = 0; ct < 2; ++ct)
                acc2[i][ct] = __builtin_amdgcn_mfma_f32_16x16x32_bf16(af2[i], bf22[ct], acc2[i][ct], 0, 0, 0);
    }
#pragma unroll
    for (int i = 0; i < 2; ++i)
#pragma unroll
        for (int ct = 0; ct < 2; ++ct) {
            int c = ct * 16 + m;
            float bv = bf2[c];
#pragma unroll
            for (int r = 0; r < 4; ++r) {
                int rr = rowBase + wr2 + i * 16 + q * 4 + r;
                out[(size_t)rr * 32 + c] = acc2[i][ct][r] + bv;
            }
        }
}

extern "C" void kernel_launch(void* const* d_in, const int* in_sizes, int n_in,
                              void* d_out, int out_size, void* d_ws, size_t ws_size,
                              hipStream_t stream) {
    const float* x    = (const float*)d_in[0];
    const int*   ei   = (const int*)d_in[1];
    const int*   batch= (const int*)d_in[2];
    const float* W1   = (const float*)d_in[3];
    const float* b1   = (const float*)d_in[4];
    const float* W2   = (const float*)d_in[5];
    const float* b2   = (const float*)d_in[6];
    const float* W3   = (const float*)d_in[7];
    const float* b3   = (const float*)d_in[8];
    const float* Wf1  = (const float*)d_in[9];
    const float* bf1  = (const float*)d_in[10];
    const float* Wf2  = (const float*)d_in[11];
    const float* bf2  = (const float*)d_in[12];
    float* out = (float*)d_out;

    const int* e_src = ei;
    const int* e_dst = ei + NEDGES;

    char* ws = (char*)d_ws;
    size_t off = 0;
    auto alloc = [&](size_t bytes) -> void* {
        void* p = (void*)(ws + off);
        off += (bytes + 255) & ~(size_t)255;
        return p;
    };
    unsigned short* X16 = (unsigned short*)alloc((size_t)NROWS * NFEAT * 2);
    unsigned short* Za  = (unsigned short*)alloc((size_t)NROWS * NFEAT * 2);   // aggregated input
    unsigned short* Ha  = (unsigned short*)alloc((size_t)NROWS * NHID * 2);    // layer outputs
    unsigned short* Zb  = (unsigned short*)alloc((size_t)NROWS * NHID * 2);    // aggregated hidden
    unsigned short* Wt1 = (unsigned short*)alloc((size_t)NHID * NFEAT * 2);    // sliced [4][256][32]
    unsigned short* Wt2 = (unsigned short*)alloc((size_t)NHID * NHID * 2);     // sliced [8][256][32]
    unsigned short* Wt3 = (unsigned short*)alloc((size_t)NHID * NHID * 2);     // sliced [8][256][32]
    unsigned short* Wf1t= (unsigned short*)alloc((size_t)NFEAT * NHID * 2);
    unsigned short* Wf2t= (unsigned short*)alloc((size_t)DOUT * NFEAT * 2);
    unsigned short* HG  = (unsigned short*)alloc((size_t)NGRAPH * NHID * 2);
    float* dinv = (float*)alloc((size_t)NNODES * 4);
    int*   cnt  = (int*)alloc((size_t)NNODES * 4);
    int*   fill = (int*)alloc((size_t)NNODES * 4);
    int*   rowp = (int*)alloc((size_t)(NNODES + 1) * 4);   // pre-offset
    int*   rowf = (int*)alloc((size_t)(NNODES + 1) * 4);   // finalized
    int2*  adj8 = (int2*)alloc((size_t)NNODES * 8 * 8);    // inline slots {src, norm} x8
    int2*  adj  = (int2*)alloc((size_t)NEDGES * 8);        // CSR overflow (entries >= 8)
    int2*  hdr  = (int2*)alloc((size_t)NNODES * 8);        // {deg, dinv^2}
    int*   part = (int*)alloc((size_t)64 * 4);
    int*   gstart = (int*)alloc((size_t)(NGRAPH + 1) * 4);
    (void)alloc(131072);   // tail pad

    const int nb = (NNODES + 1023) / 1024;   // 49

    // ---- prep: casts + zero cnt/fill/adj8 ----
    hipLaunchKernelGGL(prep_k, dim3((1250704 + 255) / 256), dim3(256), 0, stream,
                       x, X16, W1, W2, W3, Wf1, Wf2, Wt1, Wt2, Wt3, Wf1t, Wf2t, cnt, fill,
                       (int4*)adj8);
    // ---- CSR + slots + norm + graph starts ----
    hipLaunchKernelGGL(edge_hist_k, dim3((NEDGES + 255) / 256), dim3(256), 0, stream, e_dst, cnt, NEDGES);
    hipLaunchKernelGGL(scan_block_k, dim3(nb), dim3(1024), 0, stream, cnt, rowp, part, dinv, hdr, NNODES);
    hipLaunchKernelGGL(scatter_k, dim3((NEDGES + 255) / 256), dim3(256), 0, stream,
                       e_src, e_dst, rowp, part, fill, dinv, adj8, adj, rowf, batch, gstart,
                       NEDGES, NNODES, nb);

    const int ntiles = NROWS / 64;          // 782
    // ---- layer 1 ----
    hipLaunchKernelGGL((agg_k<16>), dim3((NNODES + 15) / 16), dim3(256), 0, stream,
                       X16, (const int4*)adj8, hdr, rowf, adj, Za, NNODES);
    hipLaunchKernelGGL((gemm_k<128>), dim3(512), dim3(512), 0, stream,
                       Za, Wt1, b1, Ha, NNODES, 3, ntiles);
    // ---- layer 2 ----
    hipLaunchKernelGGL((agg_k<32>), dim3((NNODES + 7) / 8), dim3(256), 0, stream,
                       Ha, (const int4*)adj8, hdr, rowf, adj, Zb, NNODES);
    hipLaunchKernelGGL((gemm_k<256>), dim3(512), dim3(512), 0, stream,
                       Zb, Wt2, b2, Ha, NNODES, 3, ntiles);
    // ---- layer 3 ----
    hipLaunchKernelGGL((agg_k<32>), dim3((NNODES + 7) / 8), dim3(256), 0, stream,
                       Ha, (const int4*)adj8, hdr, rowf, adj, Zb, NNODES);
    hipLaunchKernelGGL((gemm_k<256>), dim3(512), dim3(512), 0, stream,
                       Zb, Wt3, b3, Ha, NNODES, 3, ntiles);

    // ---- pool (one block/graph) ----
    hipLaunchKernelGGL(pool_k, dim3(NGRAPH), dim3(256), 0, stream, Ha, gstart, HG);

    // ---- MLP head (fused) ----
    hipLaunchKernelGGL(mlp_head_k, dim3(NGRAPH / 128), dim3(256), 0, stream,
                       HG, Wf1t, Wf2t, bf1, bf2, out);
}

// Round 4
// 268.310 us; speedup vs baseline: 1.2699x; 1.0442x over previous
//
#include <hip/hip_runtime.h>
#include <hip/hip_bf16.h>

#define NNODES 50000
#define NEDGES 300000
#define NGRAPH 2048
#define NFEAT  128
#define NHID   256
#define DOUT   32
#define NROWS  50048   // 64-aligned row allocation

typedef __bf16 bf16x8 __attribute__((ext_vector_type(8)));
typedef float  f32x4  __attribute__((ext_vector_type(4)));
typedef unsigned short ushort8v __attribute__((ext_vector_type(8)));
typedef __attribute__((address_space(1))) const void* gas_ptr;
typedef __attribute__((address_space(3))) void* las_ptr;

__device__ __forceinline__ float bf2f(unsigned short u) {
    return __uint_as_float(((unsigned)u) << 16);
}
__device__ __forceinline__ unsigned short f2bf(float f) {
    unsigned u = __float_as_uint(f);
    unsigned r = u + 0x7FFFu + ((u >> 16) & 1u);   // RNE
    return (unsigned short)(r >> 16);
}
__device__ __forceinline__ float sb2f(unsigned v, int k) {   // signed byte k of word -> float
    return (float)((signed char)(v >> (8 * k)));
}

// Activation arrays consumed by GEMM staging (X16, Za, Zb) are stored XOR-swizzled:
// 16B chunk ch of row r lives at chunk index (ch ^ (r&7)). Writers (prep, agg) and
// per-lane readers apply the XOR; gemm stages bytes linearly into LDS so the swizzle
// carries over and ds_read_b128 at 512B row stride is bank-conflict-free.
// Gather-side activations for layers 2-3 (Hq) are per-row int8 + f32 scale (csc):
// halves the random-gather traffic, which is the measured limiter.

// ---------- prep: cast x -> bf16 (swizzled), weights -> bf16, zero cnt/fill/adj8 ----
__global__ __launch_bounds__(256) void prep_k(const float* __restrict__ x, unsigned short* __restrict__ x16,
                                              const float* __restrict__ W1, const float* __restrict__ W2,
                                              const float* __restrict__ W3, const float* __restrict__ Wf1,
                                              const float* __restrict__ Wf2,
                                              unsigned short* __restrict__ Wt1, unsigned short* __restrict__ Wt2,
                                              unsigned short* __restrict__ Wt3, unsigned short* __restrict__ Wf1t,
                                              unsigned short* __restrict__ Wf2t,
                                              int* __restrict__ cnt, int* __restrict__ fill,
                                              int4* __restrict__ adj8z) {
    int idx = blockIdx.x * 256 + threadIdx.x;
    if (idx < 800000) {                       // x cast, one 16B chunk/thread, swizzled store
        int i = idx * 8;
        float4 a = *(const float4*)&x[i];
        float4 b = *(const float4*)&x[i + 4];
        ushort8v o = { f2bf(a.x), f2bf(a.y), f2bf(a.z), f2bf(a.w),
                       f2bf(b.x), f2bf(b.y), f2bf(b.z), f2bf(b.w) };
        int row = idx >> 4, ch = idx & 15;
        ((ushort8v*)x16)[(size_t)(row << 4) | (ch ^ (row & 7))] = o;
        return;
    }
    int t = idx - 800000;
    if (t < 200704) {
        const float* W; unsigned short* Wt; int K, N, base; bool sw;
        if      (t <  32768) { W = W1;  Wt = Wt1;  K = 128; N = 256; base = 0;      sw = true; }
        else if (t <  98304) { W = W2;  Wt = Wt2;  K = 256; N = 256; base = 32768;  sw = true; }
        else if (t < 163840) { W = W3;  Wt = Wt3;  K = 256; N = 256; base = 98304;  sw = true; }
        else if (t < 196608) { W = Wf1; Wt = Wf1t; K = 256; N = 128; base = 163840; sw = false; }
        else                 { W = Wf2; Wt = Wf2t; K = 128; N = 32;  base = 196608; sw = false; }
        int i = t - base; int n = i / K, k = i - n * K;
        unsigned short v = f2bf(W[(size_t)k * N + n]);
        if (sw) Wt[(k >> 5) * 8192 + n * 32 + (k & 31)] = v;   // sliced layout (N=256)
        else    Wt[i] = v;                                      // row-major [n][K]
        return;
    }
    t -= 200704;
    if (t < NNODES) { cnt[t] = 0; fill[t] = 0; return; }
    t -= NNODES;
    if (t < 200000) { int4 z4 = {0, 0, 0, 0}; adj8z[t] = z4; }   // zero inline slots
}

__global__ __launch_bounds__(256) void edge_hist_k(const int* __restrict__ dst, int* cnt, int E) {
    int e = blockIdx.x * 256 + threadIdx.x;
    if (e < E) atomicAdd(&cnt[dst[e]], 1);
}

// block-level scan + dinv + node header {deg, dinv^2} (chunk = 1024 nodes)
__global__ __launch_bounds__(1024) void scan_block_k(const int* __restrict__ cnt, int* __restrict__ rowp,
                                                     int* __restrict__ part, float* __restrict__ dinv,
                                                     int2* __restrict__ hdr, int n) {
    __shared__ int s[1024];
    int tid = threadIdx.x;
    int i = blockIdx.x * 1024 + tid;
    int v = (i < n) ? cnt[i] : 0;
    if (i < n) {
        float dv = rsqrtf((float)(v + 1));   // +1 self-loop
        dinv[i] = dv;
        hdr[i] = make_int2(v, __float_as_int(dv * dv));
    }
    s[tid] = v;
    __syncthreads();
    for (int off = 1; off < 1024; off <<= 1) {
        int t = (tid >= off) ? s[tid - off] : 0;
        __syncthreads();
        s[tid] += t;
        __syncthreads();
    }
    if (i < n) rowp[i] = s[tid] - v;               // exclusive, pre-offset
    if (tid == 1023) part[blockIdx.x] = s[1023];
}

// scatter: first 8 edges/dst -> inline slots adj8; rest -> CSR adj (entries >=8 only).
// Also finalizes rowp and builds graph-start table.
__global__ __launch_bounds__(256) void scatter_k(const int* __restrict__ src, const int* __restrict__ dst,
                                                 const int* __restrict__ rowp_pre, const int* __restrict__ part,
                                                 int* fill, const float* __restrict__ dinv,
                                                 int2* __restrict__ adj8, int2* __restrict__ adj,
                                                 int* __restrict__ rowp_fin,
                                                 const int* __restrict__ batch, int* __restrict__ gstart,
                                                 int E, int n, int nb) {
    __shared__ int s[64];
    int tid = threadIdx.x;
    if (tid < 64) s[tid] = (tid < nb) ? part[tid] : 0;
    __syncthreads();
    for (int off = 1; off < 64; off <<= 1) {
        int t = 0;
        if (tid < 64 && tid >= off) t = s[tid - off];
        __syncthreads();
        if (tid < 64) s[tid] += t;
        __syncthreads();
    }
    int gid = blockIdx.x * 256 + tid;
    if (gid <= n) {
        if (gid < n) {
            int ch = gid >> 10;
            int base = (ch == 0) ? 0 : s[ch - 1];
            rowp_fin[gid] = rowp_pre[gid] + base;
        } else {
            rowp_fin[n] = s[nb - 1];
        }
    }
    if (gid < n) {   // graph start offsets: gstart[g] = first node with batch >= g
        int b = batch[gid];
        int prev = (gid == 0) ? -1 : batch[gid - 1];
        for (int g = prev + 1; g <= b; ++g) gstart[g] = gid;
        if (gid == n - 1)
            for (int g = b + 1; g <= NGRAPH; ++g) gstart[g] = n;
    }
    if (gid < E) {
        int ss = src[gid], d = dst[gid];
        int f = atomicAdd(&fill[d], 1);
        int2 a; a.x = ss; a.y = __float_as_int(dinv[ss] * dinv[d]);
        if (f < 8) {
            adj8[d * 8 + f] = a;
        } else {
            int ch = d >> 10;
            int base = (ch == 0) ? 0 : s[ch - 1];
            adj[rowp_pre[d] + base + f] = a;
        }
    }
}

// ---------- slot-based aggregation, bf16 source (layer 1): z = A_hat @ T ----------
template<int CH>   // 16B chunks per row
__global__ __launch_bounds__(256) void agg_k(const unsigned short* __restrict__ T,
                                             const int4* __restrict__ adj8,
                                             const int2* __restrict__ hdr,
                                             const int* __restrict__ rowf,
                                             const int2* __restrict__ adj,
                                             unsigned short* __restrict__ z, int n) {
    int g  = threadIdx.x / CH;
    int li = threadIdx.x % CH;
    int node = blockIdx.x * (256 / CH) + g;
    if (node >= n) return;
    const ushort8v* tp = (const ushort8v*)T;
    int2 h = hdr[node];
    int deg = h.x;
    float sw = __int_as_float(h.y);
    ushort8v u = tp[(size_t)node * CH + (li ^ (node & 7))];
    int4 s4[4];
#pragma unroll
    for (int j = 0; j < 4; ++j) s4[j] = adj8[node * 4 + j];
    float ac[8];
#pragma unroll
    for (int k = 0; k < 8; ++k) ac[k] = bf2f(u[k]) * sw;
    int c[8]; float w[8];
#pragma unroll
    for (int j = 0; j < 4; ++j) {
        c[2 * j]     = s4[j].x; w[2 * j]     = __int_as_float(s4[j].y);
        c[2 * j + 1] = s4[j].z; w[2 * j + 1] = __int_as_float(s4[j].w);
    }
    ushort8v mm[8];
#pragma unroll
    for (int j = 0; j < 8; ++j) mm[j] = tp[(size_t)c[j] * CH + (li ^ (c[j] & 7))];
#pragma unroll
    for (int j = 0; j < 8; ++j)
#pragma unroll
        for (int k = 0; k < 8; ++k)
            ac[k] += bf2f(mm[j][k]) * w[j];
    if (deg > 8) {   // overflow: CSR entries >= 8
        int e0 = rowf[node], e1 = e0 + deg;
        for (int e = e0 + 8; e < e1; e += 4) {
            int2 a2[4];
#pragma unroll
            for (int j = 0; j < 4; ++j) {
                int ee = e + j;
                a2[j] = (ee < e1) ? adj[ee] : make_int2(0, 0);
            }
            ushort8v m2[4];
#pragma unroll
            for (int j = 0; j < 4; ++j) m2[j] = tp[(size_t)a2[j].x * CH + (li ^ (a2[j].x & 7))];
#pragma unroll
            for (int j = 0; j < 4; ++j)
#pragma unroll
                for (int k = 0; k < 8; ++k)
                    ac[k] += bf2f(m2[j][k]) * __int_as_float(a2[j].y);
        }
    }
    ushort8v o;
#pragma unroll
    for (int k = 0; k < 8; ++k) o[k] = f2bf(ac[k]);
    ((ushort8v*)z)[(size_t)node * CH + (li ^ (node & 7))] = o;
}

// ---------- slot-based aggregation, int8 source (layers 2-3) ----------
// Rows are 256 int8 (256B) + f32 scale (csc, 200KB -> L2-hot). Halves gather traffic.
// 32 lanes/node, 8 bytes/lane. Output z is bf16 swizzled (GEMM A operand stays bf16).
__global__ __launch_bounds__(256) void agg_q_k(const unsigned char* __restrict__ Hq,
                                               const float* __restrict__ csc,
                                               const int4* __restrict__ adj8,
                                               const int2* __restrict__ hdr,
                                               const int* __restrict__ rowf,
                                               const int2* __restrict__ adj,
                                               unsigned short* __restrict__ z, int n) {
    int g  = threadIdx.x >> 5;
    int li = threadIdx.x & 31;
    int node = blockIdx.x * 8 + g;
    if (node >= n) return;
    const uint2* qp = (const uint2*)Hq;
    int2 h = hdr[node];
    int deg = h.x;
    float swgt = __int_as_float(h.y) * csc[node];
    uint2 u = qp[(size_t)node * 32 + li];
    int4 s4[4];
#pragma unroll
    for (int j = 0; j < 4; ++j) s4[j] = adj8[node * 4 + j];
    int c[8]; float w[8];
#pragma unroll
    for (int j = 0; j < 4; ++j) {
        c[2 * j]     = s4[j].x; w[2 * j]     = __int_as_float(s4[j].y);
        c[2 * j + 1] = s4[j].z; w[2 * j + 1] = __int_as_float(s4[j].w);
    }
    uint2 mm[8];
#pragma unroll
    for (int j = 0; j < 8; ++j) mm[j] = qp[(size_t)c[j] * 32 + li];
    float ws[8];
#pragma unroll
    for (int j = 0; j < 8; ++j) ws[j] = w[j] * csc[c[j]];
    float ac[8];
#pragma unroll
    for (int k = 0; k < 4; ++k) {
        ac[k]     = sb2f(u.x, k) * swgt;
        ac[k + 4] = sb2f(u.y, k) * swgt;
    }
#pragma unroll
    for (int j = 0; j < 8; ++j)
#pragma unroll
        for (int k = 0; k < 4; ++k) {
            ac[k]     += sb2f(mm[j].x, k) * ws[j];
            ac[k + 4] += sb2f(mm[j].y, k) * ws[j];
        }
    if (deg > 8) {   // overflow: CSR entries >= 8
        int e0 = rowf[node], e1 = e0 + deg;
        for (int e = e0 + 8; e < e1; e += 4) {
            int2 a2[4];
#pragma unroll
            for (int j = 0; j < 4; ++j) {
                int ee = e + j;
                a2[j] = (ee < e1) ? adj[ee] : make_int2(0, 0);
            }
            uint2 m2[4]; float w2[4];
#pragma unroll
            for (int j = 0; j < 4; ++j) m2[j] = qp[(size_t)a2[j].x * 32 + li];
#pragma unroll
            for (int j = 0; j < 4; ++j) w2[j] = __int_as_float(a2[j].y) * csc[a2[j].x];
#pragma unroll
            for (int j = 0; j < 4; ++j)
#pragma unroll
                for (int k = 0; k < 4; ++k) {
                    ac[k]     += sb2f(m2[j].x, k) * w2[j];
                    ac[k + 4] += sb2f(m2[j].y, k) * w2[j];
                }
        }
    }
    ushort8v o;
#pragma unroll
    for (int k = 0; k < 8; ++k) o[k] = f2bf(ac[k]);
    ((ushort8v*)z)[(size_t)node * 32 + (li ^ (node & 7))] = o;
}

// ---------- MFMA GEMM: DMA-staged swizzled A-tile + register-stationary B ----------
// QOUT: epilogue emits per-row int8 + f32 scale (for the next gather) instead of bf16.
template<int K, bool QOUT>
__global__ __launch_bounds__(512, 2) void gemm_k(const unsigned short* __restrict__ A,
                                                 const unsigned short* __restrict__ Bsw,
                                                 const float* __restrict__ bias,
                                                 unsigned short* __restrict__ C,
                                                 unsigned char* __restrict__ Cq,
                                                 float* __restrict__ csc,
                                                 int M, int flags, int ntiles) {
    constexpr int CPR = K / 8;                 // 16B chunks per row
    constexpr int LP  = (64 * CPR) / 512;      // staging issues per thread (2 or 4)
    __shared__ unsigned short At[64 * K];      // swizzled A tile (16/32 KB)
    __shared__ unsigned short Et[64 * 264];    // epilogue tile (33.8 KB)
    const int tid = threadIdx.x;
    const int lane = tid & 63;
    const int wave = tid >> 6;                 // 0..7
    const int m = lane & 15, q = lane >> 4;
    const int wr = (wave >> 2) * 32;           // 0 / 32
    const int wc = (wave & 3) * 64;            // 0 / 64 / 128 / 192

    // load this wave's B slice (64 cols x K) into registers once
    bf16x8 breg[K / 32][4];
#pragma unroll
    for (int kt = 0; kt < K / 32; ++kt)
#pragma unroll
        for (int j = 0; j < 4; ++j)
            breg[kt][j] = *(const bf16x8*)&Bsw[kt * 8192 + (wc + j * 16 + m) * 32 + q * 8];

    for (int t = blockIdx.x; t < ntiles; t += gridDim.x) {
        const size_t cbase = (size_t)t * 64 * CPR;   // tile base (16B-chunk units)
        // stage A-tile: linear byte copy of the pre-swizzled global rows
#pragma unroll
        for (int p = 0; p < LP; ++p) {
            int u = p * 512 + tid;
            __builtin_amdgcn_global_load_lds((gas_ptr)(A + (cbase + u) * 8),
                                             (las_ptr)&At[(p * 512 + wave * 64) * 8], 16, 0, 0);
        }
        __syncthreads();   // staging complete (also orders vs prev tile's At reads)

        f32x4 acc[2][4] = {};
#pragma unroll
        for (int kt = 0; kt < K / 32; ++kt) {
            bf16x8 af[2];
#pragma unroll
            for (int i = 0; i < 2; ++i) {
                int lr = wr + i * 16 + m;
                af[i] = *(const bf16x8*)&At[(lr * CPR + ((kt * 4 + q) ^ (lr & 7))) * 8];
            }
#pragma unroll
            for (int i = 0; i < 2; ++i)
#pragma unroll
                for (int j = 0; j < 4; ++j)
                    acc[i][j] = __builtin_amdgcn_mfma_f32_16x16x32_bf16(af[i], breg[kt][j], acc[i][j], 0, 0, 0);
        }

        // epilogue: repack to Et (bias+relu applied), then emit
#pragma unroll
        for (int i = 0; i < 2; ++i) {
#pragma unroll
            for (int j = 0; j < 4; ++j) {
                int c = wc + j * 16 + m;
                float bv = (flags & 2) ? bias[c] : 0.f;
#pragma unroll
                for (int r = 0; r < 4; ++r) {
                    float v = acc[i][j][r] + bv;
                    if (flags & 1) v = fmaxf(v, 0.f);
                    Et[(wr + i * 16 + q * 4 + r) * 264 + c] = f2bf(v);
                }
            }
        }
        __syncthreads();   // Et ready; all At reads this tile complete

        if (QOUT) {
            // per-row int8 quantization: 8 threads/row, 32 elems/thread
            int row = tid >> 3, ch8 = tid & 7;
            int rr = t * 64 + row;
            ushort8v e[4];
#pragma unroll
            for (int k2 = 0; k2 < 4; ++k2)
                e[k2] = *(const ushort8v*)&Et[row * 264 + ch8 * 32 + k2 * 8];
            float mx = 0.f;
#pragma unroll
            for (int k2 = 0; k2 < 4; ++k2)
#pragma unroll
                for (int k = 0; k < 8; ++k) mx = fmaxf(mx, fabsf(bf2f(e[k2][k])));
            mx = fmaxf(mx, __shfl_xor(mx, 1, 64));
            mx = fmaxf(mx, __shfl_xor(mx, 2, 64));
            mx = fmaxf(mx, __shfl_xor(mx, 4, 64));
            float inv = (mx > 0.f) ? 127.f / mx : 0.f;
            unsigned pk[8];
#pragma unroll
            for (int w2 = 0; w2 < 8; ++w2) {
                unsigned p = 0;
#pragma unroll
                for (int b = 0; b < 4; ++b) {
                    int e8 = w2 * 4 + b;
                    float v = bf2f(e[e8 >> 3][e8 & 7]);
                    int qv = (int)rintf(v * inv);
                    p |= ((unsigned)(qv & 255)) << (8 * b);
                }
                pk[w2] = p;
            }
            if (rr < M) {
                uint4* dst = (uint4*)&Cq[(size_t)rr * 256 + ch8 * 32];
                dst[0] = make_uint4(pk[0], pk[1], pk[2], pk[3]);
                dst[1] = make_uint4(pk[4], pk[5], pk[6], pk[7]);
                if (ch8 == 0) csc[rr] = mx * (1.f / 127.f);
            }
        } else {
            // coalesced swizzled bf16 stores
#pragma unroll
            for (int u0 = 0; u0 < 4; ++u0) {
                int u = u0 * 512 + tid;
                int row = u >> 5, cc = u & 31;
                int rr = t * 64 + row;
                if (rr < M)
                    ((ushort8v*)C)[(size_t)rr * 32 + (cc ^ (rr & 7))] = *(const ushort8v*)&Et[row * 264 + cc * 8];
            }
        }
    }
}

// ---------- pooling: one block per graph, swizzled reads, gstart bounds ----------
__global__ __launch_bounds__(256) void pool_k(const unsigned short* __restrict__ h,
                                              const int* __restrict__ gstart,
                                              unsigned short* __restrict__ hg) {
    __shared__ float red[4][256];
    int g = blockIdx.x;
    int wave = threadIdx.x >> 6, lane = threadIdx.x & 63;
    int s = gstart[g], e = gstart[g + 1];
    int ch = lane >> 1, sub = lane & 1;
    const ushort4* hp = (const ushort4*)h;
    float4 acc = make_float4(0.f, 0.f, 0.f, 0.f);
    for (int i = s + wave; i < e; i += 4) {
        ushort4 v = hp[((size_t)i * 32 + (ch ^ (i & 7))) * 2 + sub];
        acc.x += bf2f(v.x); acc.y += bf2f(v.y); acc.z += bf2f(v.z); acc.w += bf2f(v.w);
    }
    *(float4*)&red[wave][lane * 4] = acc;
    __syncthreads();
    if (wave == 0) {
        float inv = 1.f / fmaxf((float)(e - s), 1.f);
        float v0 = red[0][lane*4+0] + red[1][lane*4+0] + red[2][lane*4+0] + red[3][lane*4+0];
        float v1 = red[0][lane*4+1] + red[1][lane*4+1] + red[2][lane*4+1] + red[3][lane*4+1];
        float v2 = red[0][lane*4+2] + red[1][lane*4+2] + red[2][lane*4+2] + red[3][lane*4+2];
        float v3 = red[0][lane*4+3] + red[1][lane*4+3] + red[2][lane*4+3] + red[3][lane*4+3];
        ushort4 o = { f2bf(v0 * inv), f2bf(v1 * inv), f2bf(v2 * inv), f2bf(v3 * inv) };
        ((ushort4*)(hg + (size_t)g * NHID))[lane] = o;
    }
}

// ---------- MLP head, fused: out = relu(HG@Wf1t^T + bf1) @ Wf2t^T + bf2 ----------
__global__ __launch_bounds__(256) void mlp_head_k(const unsigned short* __restrict__ HG,
                                                  const unsigned short* __restrict__ Wf1t,  // [128][256]
                                                  const unsigned short* __restrict__ Wf2t,  // [32][128]
                                                  const float* __restrict__ bf1, const float* __restrict__ bf2,
                                                  float* __restrict__ out) {
    __shared__ unsigned short As1[128 * 32];   // 8 KB
    __shared__ unsigned short Bs1[128 * 32];   // 8 KB
    __shared__ unsigned short R[128 * 128];    // 32 KB
    __shared__ unsigned short Bs2[32 * 128];   // 8 KB
    const int tid = threadIdx.x;
    const int lane = tid & 63, wave = tid >> 6;
    const int m = lane & 15, q = lane >> 4;
    const int rowBase = blockIdx.x * 128;
    const int wr = (wave >> 1) * 64;
    const int wc = (wave & 1) * 64;

#pragma unroll
    for (int c2 = 0; c2 < 2; ++c2) {
        const unsigned short* g = &Wf2t[(c2 * 256 + tid) * 8];
        __builtin_amdgcn_global_load_lds((gas_ptr)g, (las_ptr)&Bs2[(c2 * 256 + wave * 64) * 8], 16, 0, 0);
    }

    f32x4 acc[4][4] = {};
    for (int kt = 0; kt < 256; kt += 32) {
#pragma unroll
        for (int c2 = 0; c2 < 2; ++c2) {
            int u = c2 * 256 + tid;
            int row = u >> 2, kp = u & 3;
            const unsigned short* ga = &HG[(size_t)(rowBase + row) * 256 + kt + kp * 8];
            const unsigned short* gb = &Wf1t[(size_t)row * 256 + kt + kp * 8];
            __builtin_amdgcn_global_load_lds((gas_ptr)ga, (las_ptr)&As1[(c2 * 256 + wave * 64) * 8], 16, 0, 0);
            __builtin_amdgcn_global_load_lds((gas_ptr)gb, (las_ptr)&Bs1[(c2 * 256 + wave * 64) * 8], 16, 0, 0);
        }
        __syncthreads();
        bf16x8 af[4], bfr[4];
#pragma unroll
        for (int i = 0; i < 4; ++i) af[i] = *(const bf16x8*)&As1[(wr + i * 16 + m) * 32 + q * 8];
#pragma unroll
        for (int j = 0; j < 4; ++j) bfr[j] = *(const bf16x8*)&Bs1[(wc + j * 16 + m) * 32 + q * 8];
#pragma unroll
        for (int i = 0; i < 4; ++i)
#pragma unroll
            for (int j = 0; j < 4; ++j)
                acc[i][j] = __builtin_amdgcn_mfma_f32_16x16x32_bf16(af[i], bfr[j], acc[i][j], 0, 0, 0);
        __syncthreads();
    }
#pragma unroll
    for (int i = 0; i < 4; ++i)
#pragma unroll
        for (int j = 0; j < 4; ++j) {
            int c = wc + j * 16 + m;
            float bv = bf1[c];
#pragma unroll
            for (int r = 0; r < 4; ++r) {
                int rr = wr + i * 16 + q * 4 + r;
                R[rr * 128 + c] = f2bf(fmaxf(acc[i][j][r] + bv, 0.f));
            }
        }
    __syncthreads();

    const int wr2 = wave * 32;
    f32x4 acc2[2][2] = {};
#pragma unroll
    for (int s2 = 0; s2 < 4; ++s2) {
        bf16x8 af2[2], bf22[2];
#pragma unroll
        for (int i = 0; i < 2; ++i) af2[i] = *(const bf16x8*)&R[(wr2 + i * 16 + m) * 128 + s2 * 32 + q * 8];
#pragma unroll
        for (int ct = 0; ct < 2; ++ct) bf22[ct] = *(const bf16x8*)&Bs2[(ct * 16 + m) * 128 + s2 * 32 + q * 8];
#pragma unroll
        for (int i = 0; i < 2; ++i)
#pragma unroll
            for (int ct = 0; ct < 2; ++ct)
                acc2[i][ct] = __builtin_amdgcn_mfma_f32_16x16x32_bf16(af2[i], bf22[ct], acc2[i][ct], 0, 0, 0);
    }
#pragma unroll
    for (int i = 0; i < 2; ++i)
#pragma unroll
        for (int ct = 0; ct < 2; ++ct) {
            int c = ct * 16 + m;
            float bv = bf2[c];
#pragma unroll
            for (int r = 0; r < 4; ++r) {
                int rr = rowBase + wr2 + i * 16 + q * 4 + r;
                out[(size_t)rr * 32 + c] = acc2[i][ct][r] + bv;
            }
        }
}

extern "C" void kernel_launch(void* const* d_in, const int* in_sizes, int n_in,
                              void* d_out, int out_size, void* d_ws, size_t ws_size,
                              hipStream_t stream) {
    const float* x    = (const float*)d_in[0];
    const int*   ei   = (const int*)d_in[1];
    const int*   batch= (const int*)d_in[2];
    const float* W1   = (const float*)d_in[3];
    const float* b1   = (const float*)d_in[4];
    const float* W2   = (const float*)d_in[5];
    const float* b2   = (const float*)d_in[6];
    const float* W3   = (const float*)d_in[7];
    const float* b3   = (const float*)d_in[8];
    const float* Wf1  = (const float*)d_in[9];
    const float* bf1  = (const float*)d_in[10];
    const float* Wf2  = (const float*)d_in[11];
    const float* bf2  = (const float*)d_in[12];
    float* out = (float*)d_out;

    const int* e_src = ei;
    const int* e_dst = ei + NEDGES;

    char* ws = (char*)d_ws;
    size_t off = 0;
    auto alloc = [&](size_t bytes) -> void* {
        void* p = (void*)(ws + off);
        off += (bytes + 255) & ~(size_t)255;
        return p;
    };
    unsigned short* X16 = (unsigned short*)alloc((size_t)NROWS * NFEAT * 2);
    unsigned short* Za  = (unsigned short*)alloc((size_t)NROWS * NFEAT * 2);   // agg out, layer 1
    unsigned short* Zb  = (unsigned short*)alloc((size_t)NROWS * NHID * 2);    // agg out, layers 2-3
    unsigned short* Ha  = (unsigned short*)alloc((size_t)NROWS * NHID * 2);    // gemm3 out (bf16)
    unsigned char*  Hq  = (unsigned char*)alloc((size_t)NROWS * NHID);        // int8 activations
    float*          csc = (float*)alloc((size_t)NROWS * 4);                    // row scales
    unsigned short* Wt1 = (unsigned short*)alloc((size_t)NHID * NFEAT * 2);    // sliced [4][256][32]
    unsigned short* Wt2 = (unsigned short*)alloc((size_t)NHID * NHID * 2);     // sliced [8][256][32]
    unsigned short* Wt3 = (unsigned short*)alloc((size_t)NHID * NHID * 2);     // sliced [8][256][32]
    unsigned short* Wf1t= (unsigned short*)alloc((size_t)NFEAT * NHID * 2);
    unsigned short* Wf2t= (unsigned short*)alloc((size_t)DOUT * NFEAT * 2);
    unsigned short* HG  = (unsigned short*)alloc((size_t)NGRAPH * NHID * 2);
    float* dinv = (float*)alloc((size_t)NNODES * 4);
    int*   cnt  = (int*)alloc((size_t)NNODES * 4);
    int*   fill = (int*)alloc((size_t)NNODES * 4);
    int*   rowp = (int*)alloc((size_t)(NNODES + 1) * 4);   // pre-offset
    int*   rowf = (int*)alloc((size_t)(NNODES + 1) * 4);   // finalized
    int2*  adj8 = (int2*)alloc((size_t)NNODES * 8 * 8);    // inline slots {src, norm} x8
    int2*  adj  = (int2*)alloc((size_t)NEDGES * 8);        // CSR overflow (entries >= 8)
    int2*  hdr  = (int2*)alloc((size_t)NNODES * 8);        // {deg, dinv^2}
    int*   part = (int*)alloc((size_t)64 * 4);
    int*   gstart = (int*)alloc((size_t)(NGRAPH + 1) * 4);
    (void)alloc(131072);   // tail pad

    const int nb = (NNODES + 1023) / 1024;   // 49

    // ---- prep: casts + zero cnt/fill/adj8 ----
    hipLaunchKernelGGL(prep_k, dim3((1250704 + 255) / 256), dim3(256), 0, stream,
                       x, X16, W1, W2, W3, Wf1, Wf2, Wt1, Wt2, Wt3, Wf1t, Wf2t, cnt, fill,
                       (int4*)adj8);
    // ---- CSR + slots + norm + graph starts ----
    hipLaunchKernelGGL(edge_hist_k, dim3((NEDGES + 255) / 256), dim3(256), 0, stream, e_dst, cnt, NEDGES);
    hipLaunchKernelGGL(scan_block_k, dim3(nb), dim3(1024), 0, stream, cnt, rowp, part, dinv, hdr, NNODES);
    hipLaunchKernelGGL(scatter_k, dim3((NEDGES + 255) / 256), dim3(256), 0, stream,
                       e_src, e_dst, rowp, part, fill, dinv, adj8, adj, rowf, batch, gstart,
                       NEDGES, NNODES, nb);

    const int ntiles = NROWS / 64;          // 782
    // ---- layer 1: Za = A_hat X (bf16); Hq,csc = q8(relu(Za@W1+b1)) ----
    hipLaunchKernelGGL((agg_k<16>), dim3((NNODES + 15) / 16), dim3(256), 0, stream,
                       X16, (const int4*)adj8, hdr, rowf, adj, Za, NNODES);
    hipLaunchKernelGGL((gemm_k<128, true>), dim3(512), dim3(512), 0, stream,
                       Za, Wt1, b1, (unsigned short*)nullptr, Hq, csc, NNODES, 3, ntiles);
    // ---- layer 2: Zb = A_hat Hq (int8 gather); Hq,csc = q8(relu(Zb@W2+b2)) ----
    hipLaunchKernelGGL(agg_q_k, dim3((NNODES + 7) / 8), dim3(256), 0, stream,
                       Hq, csc, (const int4*)adj8, hdr, rowf, adj, Zb, NNODES);
    hipLaunchKernelGGL((gemm_k<256, true>), dim3(512), dim3(512), 0, stream,
                       Zb, Wt2, b2, (unsigned short*)nullptr, Hq, csc, NNODES, 3, ntiles);
    // ---- layer 3: Zb = A_hat Hq; Ha = relu(Zb@W3+b3) (bf16 for pool) ----
    hipLaunchKernelGGL(agg_q_k, dim3((NNODES + 7) / 8), dim3(256), 0, stream,
                       Hq, csc, (const int4*)adj8, hdr, rowf, adj, Zb, NNODES);
    hipLaunchKernelGGL((gemm_k<256, false>), dim3(512), dim3(512), 0, stream,
                       Zb, Wt3, b3, Ha, Hq, csc, NNODES, 3, ntiles);

    // ---- pool (one block/graph) ----
    hipLaunchKernelGGL(pool_k, dim3(NGRAPH), dim3(256), 0, stream, Ha, gstart, HG);

    // ---- MLP head (fused) ----
    hipLaunchKernelGGL(mlp_head_k, dim3(NGRAPH / 128), dim3(256), 0, stream,
                       HG, Wf1t, Wf2t, bf1, bf2, out);
}